// Round 1
// baseline (839.301 us; speedup 1.0000x reference)
//
#include <hip/hip_runtime.h>
#include <hip/hip_bf16.h>

#define TPB 256

// ---------------------------------------------------------------------------
// K1: hist[r][f] = 1e-4 * sum_{o<band} Xs[tril_col(r,o)][f]
// (position_weight is hardcoded 1e-4 in the reference forward)
// ---------------------------------------------------------------------------
__global__ void hist_kernel(const float* __restrict__ Xs, const int* __restrict__ tril,
                            float* __restrict__ hist, int S, int band, int F) {
    int gid = blockIdx.x * blockDim.x + threadIdx.x;
    if (gid >= S * F) return;
    int r = gid / F;
    int f = gid - r * F;
    const int* tre = tril + (size_t)r * band * 2;
    float acc = 0.f;
    for (int o = 0; o < band; ++o) {
        int c = tre[o * 2 + 1];
        acc += Xs[(size_t)c * F + f];
    }
    hist[gid] = acc * 1e-4f;
}

// ---------------------------------------------------------------------------
// K2: W1sum[f][c] = sum_{p<PW} W1[p*F + f][c]   (folds the 10 identical
// concat_history copies into one 64x256 weight block)
// ---------------------------------------------------------------------------
__global__ void w1sum_kernel(const float* __restrict__ W1, float* __restrict__ W1sum,
                             int F, int H, int PW) {
    int t = blockIdx.x * blockDim.x + threadIdx.x;
    if (t >= F * H) return;
    int f = t / H, c = t - f * H;
    float s = 0.f;
    for (int p = 0; p < PW; ++p) s += W1[((size_t)(p * F + f)) * H + c];
    W1sum[t] = s;
}

// ---------------------------------------------------------------------------
// K3: Ahist[s][:] = hist[s][:] @ W1sum + b1     (S x 64 x 256 GEMM)
// 32 rows/block, 256 threads, 4x8 micro-tile; thread rows = tr + 8*i so the
// 8 broadcast LDS rows land in 8 distinct bank-groups (stride 68 ≡ 4 mod 32).
// ---------------------------------------------------------------------------
__global__ __launch_bounds__(TPB, 2) void ahist_kernel(
    const float* __restrict__ hist, const float* __restrict__ W1sum,
    const float* __restrict__ b1, float* __restrict__ Ahist, int S)
{
    __shared__ float sA[32][68];
    const int d0 = blockIdx.x * 32;
    const int tid = threadIdx.x;
    const int tc = tid & 31;
    const int tr = tid >> 5;
    const int c0 = tc * 8;

    for (int i = tid; i < 512; i += TPB) {
        int r = i >> 4, q = i & 15;
        int rg = d0 + r; if (rg > S - 1) rg = S - 1;
        *(float4*)&sA[r][q * 4] = *(const float4*)&hist[(size_t)rg * 64 + q * 4];
    }
    __syncthreads();

    float acc[4][8];
    #pragma unroll
    for (int i = 0; i < 4; ++i)
        #pragma unroll
        for (int j = 0; j < 8; ++j) acc[i][j] = 0.f;

    for (int k4 = 0; k4 < 16; ++k4) {
        float4 a[4];
        #pragma unroll
        for (int i = 0; i < 4; ++i) a[i] = *(const float4*)&sA[tr + 8 * i][k4 * 4];
        #pragma unroll
        for (int kk = 0; kk < 4; ++kk) {
            const float* wr = &W1sum[(k4 * 4 + kk) * 256];
            float4 bA = *(const float4*)&wr[c0];
            float4 bB = *(const float4*)&wr[c0 + 4];
            #pragma unroll
            for (int i = 0; i < 4; ++i) {
                float av = kk == 0 ? a[i].x : kk == 1 ? a[i].y : kk == 2 ? a[i].z : a[i].w;
                acc[i][0] += av * bA.x; acc[i][1] += av * bA.y;
                acc[i][2] += av * bA.z; acc[i][3] += av * bA.w;
                acc[i][4] += av * bB.x; acc[i][5] += av * bB.y;
                acc[i][6] += av * bB.z; acc[i][7] += av * bB.w;
            }
        }
    }

    float4 b1a = *(const float4*)&b1[c0];
    float4 b1b = *(const float4*)&b1[c0 + 4];
    #pragma unroll
    for (int i = 0; i < 4; ++i) {
        int row = d0 + tr + 8 * i;
        if (row < S) {
            float4 oA = make_float4(acc[i][0] + b1a.x, acc[i][1] + b1a.y,
                                    acc[i][2] + b1a.z, acc[i][3] + b1a.w);
            float4 oB = make_float4(acc[i][4] + b1b.x, acc[i][5] + b1b.y,
                                    acc[i][6] + b1b.z, acc[i][7] + b1b.w);
            *(float4*)&Ahist[(size_t)row * 256 + c0] = oA;
            *(float4*)&Ahist[(size_t)row * 256 + c0 + 4] = oB;
        }
    }
}

// ---------------------------------------------------------------------------
// K4: fused 3-layer MLP per disp row.
// z1 = Ahist[sec] + dispF @ W1b ; h1 = elu ; z2 = h1 @ W2 + b2 ; h2 = elu ;
// u = h2 @ W3 + b3.  h2 never touches LDS (layer-3 dot folded into registers
// + 32-lane shuffle reduce).
// ---------------------------------------------------------------------------
__global__ __launch_bounds__(TPB, 2) void mlp_kernel(
    const float* __restrict__ dispF, const int* __restrict__ sec,
    const float* __restrict__ Ahist, const float* __restrict__ W1b,
    const float* __restrict__ W2, const float* __restrict__ b2,
    const float* __restrict__ W3, const float* __restrict__ b3,
    float* __restrict__ u, int ND)
{
    __shared__ float sA[32][68];    // dispF tile (stride 68: 16B aligned, ≡4 mod 32)
    __shared__ float sH[32][260];   // h1 tile    (stride 260: 16B aligned, ≡4 mod 32)
    __shared__ int sSec[32];

    const int d0 = blockIdx.x * 32;
    const int tid = threadIdx.x;
    const int tc = tid & 31;
    const int tr = tid >> 5;
    const int c0 = tc * 8;

    for (int i = tid; i < 512; i += TPB) {
        int r = i >> 4, q = i & 15;
        int rg = d0 + r; if (rg > ND - 1) rg = ND - 1;
        *(float4*)&sA[r][q * 4] = *(const float4*)&dispF[(size_t)rg * 64 + q * 4];
    }
    if (tid < 32) {
        int rg = d0 + tid; if (rg > ND - 1) rg = ND - 1;
        sSec[tid] = sec[rg];
    }
    __syncthreads();

    // ---- layer 1: acc = sA @ W1b ----
    float acc[4][8];
    #pragma unroll
    for (int i = 0; i < 4; ++i)
        #pragma unroll
        for (int j = 0; j < 8; ++j) acc[i][j] = 0.f;

    for (int k4 = 0; k4 < 16; ++k4) {
        float4 a[4];
        #pragma unroll
        for (int i = 0; i < 4; ++i) a[i] = *(const float4*)&sA[tr + 8 * i][k4 * 4];
        #pragma unroll
        for (int kk = 0; kk < 4; ++kk) {
            const float* wr = &W1b[(k4 * 4 + kk) * 256];
            float4 bA = *(const float4*)&wr[c0];
            float4 bB = *(const float4*)&wr[c0 + 4];
            #pragma unroll
            for (int i = 0; i < 4; ++i) {
                float av = kk == 0 ? a[i].x : kk == 1 ? a[i].y : kk == 2 ? a[i].z : a[i].w;
                acc[i][0] += av * bA.x; acc[i][1] += av * bA.y;
                acc[i][2] += av * bA.z; acc[i][3] += av * bA.w;
                acc[i][4] += av * bB.x; acc[i][5] += av * bB.y;
                acc[i][6] += av * bB.z; acc[i][7] += av * bB.w;
            }
        }
    }

    // ---- add Ahist (b1 folded in), elu, stash h1 in LDS ----
    #pragma unroll
    for (int i = 0; i < 4; ++i) {
        int r = tr + 8 * i;
        size_t srow = (size_t)sSec[r] * 256;
        float4 hA = *(const float4*)&Ahist[srow + c0];
        float4 hB = *(const float4*)&Ahist[srow + c0 + 4];
        float z[8];
        z[0] = acc[i][0] + hA.x; z[1] = acc[i][1] + hA.y;
        z[2] = acc[i][2] + hA.z; z[3] = acc[i][3] + hA.w;
        z[4] = acc[i][4] + hB.x; z[5] = acc[i][5] + hB.y;
        z[6] = acc[i][6] + hB.z; z[7] = acc[i][7] + hB.w;
        #pragma unroll
        for (int j = 0; j < 8; ++j) z[j] = z[j] > 0.f ? z[j] : __expf(z[j]) - 1.f;
        *(float4*)&sH[r][c0]     = make_float4(z[0], z[1], z[2], z[3]);
        *(float4*)&sH[r][c0 + 4] = make_float4(z[4], z[5], z[6], z[7]);
    }
    __syncthreads();

    // ---- layer 2: acc2 = h1 @ W2 ----
    float acc2[4][8];
    #pragma unroll
    for (int i = 0; i < 4; ++i)
        #pragma unroll
        for (int j = 0; j < 8; ++j) acc2[i][j] = 0.f;

    for (int k4 = 0; k4 < 64; ++k4) {
        float4 a[4];
        #pragma unroll
        for (int i = 0; i < 4; ++i) a[i] = *(const float4*)&sH[tr + 8 * i][k4 * 4];
        #pragma unroll
        for (int kk = 0; kk < 4; ++kk) {
            const float* wr = &W2[(k4 * 4 + kk) * 256];
            float4 bA = *(const float4*)&wr[c0];
            float4 bB = *(const float4*)&wr[c0 + 4];
            #pragma unroll
            for (int i = 0; i < 4; ++i) {
                float av = kk == 0 ? a[i].x : kk == 1 ? a[i].y : kk == 2 ? a[i].z : a[i].w;
                acc2[i][0] += av * bA.x; acc2[i][1] += av * bA.y;
                acc2[i][2] += av * bA.z; acc2[i][3] += av * bA.w;
                acc2[i][4] += av * bB.x; acc2[i][5] += av * bB.y;
                acc2[i][6] += av * bB.z; acc2[i][7] += av * bB.w;
            }
        }
    }

    // ---- +b2, elu, fold layer 3 (dot with W3), shuffle-reduce over tc ----
    float4 b2a = *(const float4*)&b2[c0];
    float4 b2b = *(const float4*)&b2[c0 + 4];
    float4 w3a = *(const float4*)&W3[c0];
    float4 w3b = *(const float4*)&W3[c0 + 4];
    float bb[8] = {b2a.x, b2a.y, b2a.z, b2a.w, b2b.x, b2b.y, b2b.z, b2b.w};
    float ww[8] = {w3a.x, w3a.y, w3a.z, w3a.w, w3b.x, w3b.y, w3b.z, w3b.w};
    float b3v = b3[0];

    #pragma unroll
    for (int i = 0; i < 4; ++i) {
        float up = 0.f;
        #pragma unroll
        for (int j = 0; j < 8; ++j) {
            float z = acc2[i][j] + bb[j];
            z = z > 0.f ? z : __expf(z) - 1.f;
            up += z * ww[j];
        }
        #pragma unroll
        for (int off = 16; off > 0; off >>= 1) up += __shfl_xor(up, off, 32);
        if (tc == 0) {
            int row = d0 + tr + 8 * i;
            if (row < ND) u[row] = up + b3v;
        }
    }
}

// ---------------------------------------------------------------------------
// K5: per-session loss + argmax/top-2 precision counts (exact top_k
// tie-break semantics: value desc, item index asc; if only one distinct
// disp item, second index = first zero-valued item).
// ---------------------------------------------------------------------------
template <int PER>
__global__ void session_kernel(const float* __restrict__ u, const int* __restrict__ clickSub,
                               const int* __restrict__ clickIdx, const int* __restrict__ dispIdx,
                               float* __restrict__ pLoss, int* __restrict__ pP1,
                               int* __restrict__ pP2, int S) {
    int s = blockIdx.x * blockDim.x + threadIdx.x;
    float lossv = 0.f; int p1 = 0, p2 = 0;
    if (s < S) {
        int base = s * PER;
        float ev[PER]; int it[PER];
        float sum_exp = 0.f;
        #pragma unroll
        for (int i = 0; i < PER; ++i) {
            float uu = u[base + i];
            ev[i] = expf(uu);
            sum_exp += ev[i];
            it[i] = dispIdx[(size_t)(base + i) * 2 + 1];
        }
        int crow = clickSub[s];
        lossv = -u[crow] + logf(sum_exp + 1.f);

        float bestv = -1.f; int besti = 0x7FFFFFFF;
        float secv = -1.f;  int seci = 0x7FFFFFFF;
        int ndist = 0;
        #pragma unroll
        for (int i = 0; i < PER; ++i) {
            bool first = true; float tot = 0.f;
            #pragma unroll
            for (int j = 0; j < PER; ++j) {
                if (it[j] == it[i]) { tot += ev[j]; if (j < i) first = false; }
            }
            if (first) {
                ndist++;
                if (tot > bestv || (tot == bestv && it[i] < besti)) {
                    secv = bestv; seci = besti;
                    bestv = tot;  besti = it[i];
                } else if (tot > secv || (tot == secv && it[i] < seci)) {
                    secv = tot; seci = it[i];
                }
            }
        }
        if (ndist < 2) seci = (besti == 0) ? 1 : 0;
        int citem = clickIdx[s * 2 + 1];
        p1 = (citem == besti) ? 1 : 0;
        p2 = (citem == besti || citem == seci) ? 1 : 0;
    }
    __shared__ float rf[TPB]; __shared__ int r1[TPB]; __shared__ int r2[TPB];
    int t = threadIdx.x;
    rf[t] = lossv; r1[t] = p1; r2[t] = p2;
    __syncthreads();
    for (int off = TPB / 2; off > 0; off >>= 1) {
        if (t < off) { rf[t] += rf[t + off]; r1[t] += r1[t + off]; r2[t] += r2[t + off]; }
        __syncthreads();
    }
    if (t == 0) { pLoss[blockIdx.x] = rf[0]; pP1[blockIdx.x] = r1[0]; pP2[blockIdx.x] = r2[0]; }
}

// ---------------------------------------------------------------------------
// K6: reduce block partials, emit the 7 scalar outputs.
// ---------------------------------------------------------------------------
__global__ void finalize_kernel(const float* __restrict__ pLoss, const int* __restrict__ pP1,
                                const int* __restrict__ pP2, int nb, float event_cnt,
                                float* __restrict__ out) {
    __shared__ float sf[TPB]; __shared__ int s1[TPB]; __shared__ int s2[TPB];
    int t = threadIdx.x;
    float lf = 0.f; int a1 = 0, a2 = 0;
    for (int i = t; i < nb; i += TPB) { lf += pLoss[i]; a1 += pP1[i]; a2 += pP2[i]; }
    sf[t] = lf; s1[t] = a1; s2[t] = a2;
    __syncthreads();
    for (int off = TPB / 2; off > 0; off >>= 1) {
        if (t < off) { sf[t] += sf[t + off]; s1[t] += s1[t + off]; s2[t] += s2[t + off]; }
        __syncthreads();
    }
    if (t == 0) {
        float ls = sf[0];
        float p1 = (float)s1[0];
        float p2 = (float)s2[0];
        out[0] = ls / event_cnt;
        out[1] = p1 / event_cnt;
        out[2] = p2 / event_cnt;
        out[3] = ls;
        out[4] = p1;
        out[5] = p2;
        out[6] = event_cnt;
    }
}

// ---------------------------------------------------------------------------
extern "C" void kernel_launch(void* const* d_in, const int* in_sizes, int n_in,
                              void* d_out, int out_size, void* d_ws, size_t ws_size,
                              hipStream_t stream) {
    const float* dispF    = (const float*)d_in[0];
    const float* Xs       = (const float*)d_in[1];
    const float* W1       = (const float*)d_in[2];
    const float* b1       = (const float*)d_in[3];
    const float* W2       = (const float*)d_in[4];
    const float* b2       = (const float*)d_in[5];
    const float* W3       = (const float*)d_in[6];
    const float* b3       = (const float*)d_in[7];
    const int*   tril     = (const int*)d_in[8];
    const int*   sec      = (const int*)d_in[10];
    const int*   clickSub = (const int*)d_in[11];
    const int*   clickIdx = (const int*)d_in[12];
    const int*   dispIdx  = (const int*)d_in[13];

    const int S    = in_sizes[11];
    const int ND   = in_sizes[10];
    const int F    = in_sizes[1] / S;          // 64
    const int H    = in_sizes[3];              // 256
    const int NT   = in_sizes[9];
    const int BAND = NT / S;                   // 20
    const int PW   = in_sizes[2] / (F * H) - 1; // 10
    const int per  = ND / S;                   // 10

    float* ws    = (float*)d_ws;
    float* hist  = ws;                                  // S*F
    float* W1sum = hist + (size_t)S * F;                // F*H
    float* Ahist = W1sum + (size_t)F * H;               // S*H
    float* u     = Ahist + (size_t)S * H;               // ND
    const int nb5 = (S + TPB - 1) / TPB;
    float* pLoss = u + ND;                              // nb5
    int*   pP1   = (int*)(pLoss + nb5);                 // nb5
    int*   pP2   = pP1 + nb5;                           // nb5

    const float* W1b = W1 + (size_t)(PW * F) * H;       // last 64x256 block of W1

    hist_kernel<<<(S * F + TPB - 1) / TPB, TPB, 0, stream>>>(Xs, tril, hist, S, BAND, F);
    w1sum_kernel<<<(F * H + TPB - 1) / TPB, TPB, 0, stream>>>(W1, W1sum, F, H, PW);
    ahist_kernel<<<(S + 31) / 32, TPB, 0, stream>>>(hist, W1sum, b1, Ahist, S);
    mlp_kernel<<<(ND + 31) / 32, TPB, 0, stream>>>(dispF, sec, Ahist, W1b, W2, b2, W3, b3, u, ND);
    session_kernel<10><<<nb5, TPB, 0, stream>>>(u, clickSub, clickIdx, dispIdx, pLoss, pP1, pP2, S);
    finalize_kernel<<<1, TPB, 0, stream>>>(pLoss, pP1, pP2, nb5, (float)S, (float*)d_out);
}

// Round 2
// 270.905 us; speedup vs baseline: 3.0981x; 3.0981x over previous
//
#include <hip/hip_runtime.h>
#include <hip/hip_bf16.h>

#define TPB 256

typedef _Float16 f16x8 __attribute__((ext_vector_type(8)));
typedef float    f32x16 __attribute__((ext_vector_type(16)));
typedef unsigned int uint;
typedef uint u32x4 __attribute__((ext_vector_type(4)));

// ---------------------------------------------------------------------------
// K1: hist[r][f] = 1e-4 * sum_{o<band} Xs[tril_col(r,o)][f]
// ---------------------------------------------------------------------------
__global__ void hist_kernel(const float* __restrict__ Xs, const int* __restrict__ tril,
                            float* __restrict__ hist, int S, int band, int F) {
    int gid = blockIdx.x * blockDim.x + threadIdx.x;
    if (gid >= S * F) return;
    int r = gid / F;
    int f = gid - r * F;
    const int* tre = tril + (size_t)r * band * 2;
    float acc = 0.f;
    for (int o = 0; o < band; ++o) {
        int c = tre[o * 2 + 1];
        acc += Xs[(size_t)c * F + f];
    }
    hist[gid] = acc * 1e-4f;
}

// ---------------------------------------------------------------------------
// K2: W1sum[f][c] = sum_{p<PW} W1[p*F + f][c]
// ---------------------------------------------------------------------------
__global__ void w1sum_kernel(const float* __restrict__ W1, float* __restrict__ W1sum,
                             int F, int H, int PW) {
    int t = blockIdx.x * blockDim.x + threadIdx.x;
    if (t >= F * H) return;
    int f = t / H, c = t - f * H;
    float s = 0.f;
    for (int p = 0; p < PW; ++p) s += W1[((size_t)(p * F + f)) * H + c];
    W1sum[t] = s;
}

// ---------------------------------------------------------------------------
// K3: Ahist[s][:] = hist[s][:] @ W1sum + b1   (fp32 vector; small)
// ---------------------------------------------------------------------------
__global__ __launch_bounds__(TPB, 2) void ahist_kernel(
    const float* __restrict__ hist, const float* __restrict__ W1sum,
    const float* __restrict__ b1, float* __restrict__ Ahist, int S)
{
    __shared__ float sA[32][68];
    const int d0 = blockIdx.x * 32;
    const int tid = threadIdx.x;
    const int tc = tid & 31;
    const int tr = tid >> 5;
    const int c0 = tc * 8;

    for (int i = tid; i < 512; i += TPB) {
        int r = i >> 4, q = i & 15;
        int rg = d0 + r; if (rg > S - 1) rg = S - 1;
        *(float4*)&sA[r][q * 4] = *(const float4*)&hist[(size_t)rg * 64 + q * 4];
    }
    __syncthreads();

    float acc[4][8];
    #pragma unroll
    for (int i = 0; i < 4; ++i)
        #pragma unroll
        for (int j = 0; j < 8; ++j) acc[i][j] = 0.f;

    for (int k4 = 0; k4 < 16; ++k4) {
        float4 a[4];
        #pragma unroll
        for (int i = 0; i < 4; ++i) a[i] = *(const float4*)&sA[tr + 8 * i][k4 * 4];
        #pragma unroll
        for (int kk = 0; kk < 4; ++kk) {
            const float* wr = &W1sum[(k4 * 4 + kk) * 256];
            float4 bA = *(const float4*)&wr[c0];
            float4 bB = *(const float4*)&wr[c0 + 4];
            #pragma unroll
            for (int i = 0; i < 4; ++i) {
                float av = kk == 0 ? a[i].x : kk == 1 ? a[i].y : kk == 2 ? a[i].z : a[i].w;
                acc[i][0] += av * bA.x; acc[i][1] += av * bA.y;
                acc[i][2] += av * bA.z; acc[i][3] += av * bA.w;
                acc[i][4] += av * bB.x; acc[i][5] += av * bB.y;
                acc[i][6] += av * bB.z; acc[i][7] += av * bB.w;
            }
        }
    }

    float4 b1a = *(const float4*)&b1[c0];
    float4 b1b = *(const float4*)&b1[c0 + 4];
    #pragma unroll
    for (int i = 0; i < 4; ++i) {
        int row = d0 + tr + 8 * i;
        if (row < S) {
            float4 oA = make_float4(acc[i][0] + b1a.x, acc[i][1] + b1a.y,
                                    acc[i][2] + b1a.z, acc[i][3] + b1a.w);
            float4 oB = make_float4(acc[i][4] + b1b.x, acc[i][5] + b1b.y,
                                    acc[i][6] + b1b.z, acc[i][7] + b1b.w);
            *(float4*)&Ahist[(size_t)row * 256 + c0] = oA;
            *(float4*)&Ahist[(size_t)row * 256 + c0 + 4] = oB;
        }
    }
}

// ---------------------------------------------------------------------------
// K-prep: transposed fp16 hi/lo splits of W1b and W2.
// W1bT_hi/lo[n][k] (256x64), W2T_hi/lo[n][k] (256x256)
// ---------------------------------------------------------------------------
__global__ void prep_kernel(const float* __restrict__ W1, const float* __restrict__ W2,
                            _Float16* __restrict__ W1bT_hi, _Float16* __restrict__ W1bT_lo,
                            _Float16* __restrict__ W2T_hi, _Float16* __restrict__ W2T_lo,
                            int PWF) {
    int t = blockIdx.x * blockDim.x + threadIdx.x;
    if (t < 64 * 256) {
        int n = t >> 6, k = t & 63;
        float x = W1[(size_t)(PWF + k) * 256 + n];
        _Float16 h = (_Float16)x;
        W1bT_hi[t] = h;
        W1bT_lo[t] = (_Float16)(x - (float)h);
    }
    int t2 = t - 64 * 256;
    if (t2 >= 0 && t2 < 256 * 256) {
        int n = t2 >> 8, k = t2 & 255;
        float x = W2[(size_t)k * 256 + n];
        _Float16 h = (_Float16)x;
        W2T_hi[t2] = h;
        W2T_lo[t2] = (_Float16)(x - (float)h);
    }
}

__device__ __forceinline__ uint pack2f16(float lo_v, float hi_v) {
    _Float16 a = (_Float16)lo_v, b = (_Float16)hi_v;
    unsigned short ua = __builtin_bit_cast(unsigned short, a);
    unsigned short ub = __builtin_bit_cast(unsigned short, b);
    return (uint)ua | ((uint)ub << 16);
}

__device__ __forceinline__ float elu_f(float z) {
    return z > 0.f ? z : __expf(z) - 1.f;
}

// ---------------------------------------------------------------------------
// K4: fused MLP via split-fp16 MFMA (v_mfma_f32_32x32x16_f16).
// Block = 256 thr = 4 waves, 128 rows. Wave w owns n-tiles {2w,2w+1}.
// layer1: z1 = dispF@W1b (A 2-term x B 2-term, 3 MFMA) + Ahist[row/10] (C-init)
// h1 = elu(z1) -> LDS packed u32 (fp16 pair cols c,c+32), XOR-swizzled units
// layer2: z2 = h1 @ W2 (h1 fp16 single, W2 hi/lo: 2 MFMA); each 32B LDS read
//         yields A-frags for TWO k-steps (lo/hi halves).
// layer3: per-lane dot with W3, LDS reduce over 32 cols, +b3, store u.
// ---------------------------------------------------------------------------
__global__ __launch_bounds__(TPB, 2) void mlp_mfma_kernel(
    const float* __restrict__ dispF, const float* __restrict__ Ahist,
    const _Float16* __restrict__ W1bT_hi, const _Float16* __restrict__ W1bT_lo,
    const _Float16* __restrict__ W2T_hi, const _Float16* __restrict__ W2T_lo,
    const float* __restrict__ b2, const float* __restrict__ W3,
    const float* __restrict__ b3, float* __restrict__ u,
    int ND, int per, float inv_per)
{
    __shared__ uint smem[16384];   // 64KB: h1x[128][128] u32, later pbuf[4][32][128] f32

    const int tid = threadIdx.x;
    const int w   = tid >> 6;        // wave 0..3
    const int l   = tid & 63;
    const int lr  = l & 31;          // A row-in-tile / B,C col-in-tile
    const int hh  = l >> 5;          // lane half
    const int R0  = blockIdx.x * 128;
    const int NDm1 = ND - 1;
    const int c0 = (2 * w) * 32 + lr;       // wave's col for nt=0
    const int c1 = (2 * w + 1) * 32 + lr;   // nt=1

    f32x16 acc[4][2];

    // ---- acc init = Ahist gather (C-frag layout: col=lane&31, row=(reg&3)+8*(reg>>2)+4*hh)
    #pragma unroll
    for (int m = 0; m < 4; ++m) {
        #pragma unroll
        for (int rq = 0; rq < 4; ++rq) {
            #pragma unroll
            for (int rr = 0; rr < 4; ++rr) {
                int rg = R0 + m * 32 + rq * 8 + 4 * hh + rr;
                if (rg > NDm1) rg = NDm1;
                int srow = (int)((float)rg * inv_per);
                srow += ((srow + 1) * per <= rg) ? 1 : 0;
                const float* ap = Ahist + (size_t)srow * 256;
                acc[m][0][rq * 4 + rr] = ap[c0];
                acc[m][1][rq * 4 + rr] = ap[c1];
            }
        }
    }

    // ---- layer 1: 3-term split-fp16 MFMA over K=64 ----
    #pragma unroll
    for (int ks = 0; ks < 4; ++ks) {
        f16x8 Dhi[4], Dlo[4];
        #pragma unroll
        for (int m = 0; m < 4; ++m) {
            int rg = R0 + m * 32 + lr; if (rg > NDm1) rg = NDm1;
            const float* p = dispF + (size_t)rg * 64 + ks * 16 + 8 * hh;
            float4 x0 = *(const float4*)p;
            float4 x1 = *(const float4*)(p + 4);
            float xs[8] = {x0.x, x0.y, x0.z, x0.w, x1.x, x1.y, x1.z, x1.w};
            #pragma unroll
            for (int e = 0; e < 8; ++e) {
                _Float16 h = (_Float16)xs[e];
                Dhi[m][e] = h;
                Dlo[m][e] = (_Float16)(xs[e] - (float)h);
            }
        }
        #pragma unroll
        for (int nt = 0; nt < 2; ++nt) {
            int n = (2 * w + nt) * 32 + lr;
            const _Float16* bp = W1bT_hi + n * 64 + ks * 16 + 8 * hh;
            const _Float16* bq = W1bT_lo + n * 64 + ks * 16 + 8 * hh;
            f16x8 Bhi = *(const f16x8*)bp;
            f16x8 Blo = *(const f16x8*)bq;
            #pragma unroll
            for (int m = 0; m < 4; ++m) {
                acc[m][nt] = __builtin_amdgcn_mfma_f32_32x32x16_f16(Dhi[m], Bhi, acc[m][nt], 0, 0, 0);
                acc[m][nt] = __builtin_amdgcn_mfma_f32_32x32x16_f16(Dlo[m], Bhi, acc[m][nt], 0, 0, 0);
                acc[m][nt] = __builtin_amdgcn_mfma_f32_32x32x16_f16(Dhi[m], Blo, acc[m][nt], 0, 0, 0);
            }
        }
    }

    // ---- h1 = elu(z1); pack (col, col+32) as u32; swizzled LDS write ----
    #pragma unroll
    for (int m = 0; m < 4; ++m) {
        #pragma unroll
        for (int rq = 0; rq < 4; ++rq) {
            #pragma unroll
            for (int rr = 0; rr < 4; ++rr) {
                float z0 = elu_f(acc[m][0][rq * 4 + rr]);
                float z1v = elu_f(acc[m][1][rq * 4 + rr]);
                uint pk = pack2f16(z0, z1v);
                int row = m * 32 + rq * 8 + 4 * hh + rr;
                int unit = w * 8 + (lr >> 2);
                int phys = unit ^ (row & 7);
                smem[row * 128 + (phys << 2) + (lr & 3)] = pk;
            }
        }
    }

    // ---- re-init acc with b2 ----
    float b2v0 = b2[c0], b2v1 = b2[c1];
    #pragma unroll
    for (int m = 0; m < 4; ++m)
        #pragma unroll
        for (int r = 0; r < 16; ++r) { acc[m][0][r] = b2v0; acc[m][1][r] = b2v1; }

    __syncthreads();

    // ---- layer 2: pair-steps; one 32B read -> A-frags for k-steps ks_lo, ks_lo+2 ----
    #pragma unroll
    for (int ps = 0; ps < 8; ++ps) {
        const int ks_lo = (ps >> 1) * 4 + (ps & 1);
        const int u0 = (ps >> 1) * 8 + (ps & 1) * 4 + 2 * hh;   // 16B-unit index (even)
        f16x8 A0[4], A1[4];
        #pragma unroll
        for (int m = 0; m < 4; ++m) {
            int row = m * 32 + lr;
            u32x4 q0 = *(const u32x4*)&smem[row * 128 + ((u0 ^ (row & 7)) << 2)];
            u32x4 q1 = *(const u32x4*)&smem[row * 128 + (((u0 + 1) ^ (row & 7)) << 2)];
            u32x4 lo, hi;
            lo.x = (q0.x & 0xffffu) | (q0.y << 16);
            lo.y = (q0.z & 0xffffu) | (q0.w << 16);
            lo.z = (q1.x & 0xffffu) | (q1.y << 16);
            lo.w = (q1.z & 0xffffu) | (q1.w << 16);
            hi.x = (q0.x >> 16) | (q0.y & 0xffff0000u);
            hi.y = (q0.z >> 16) | (q0.w & 0xffff0000u);
            hi.z = (q1.x >> 16) | (q1.y & 0xffff0000u);
            hi.w = (q1.z >> 16) | (q1.w & 0xffff0000u);
            A0[m] = __builtin_bit_cast(f16x8, lo);
            A1[m] = __builtin_bit_cast(f16x8, hi);
        }
        #pragma unroll
        for (int half = 0; half < 2; ++half) {
            const int ks = ks_lo + 2 * half;
            const int kk = ks * 16 + 8 * hh;
            #pragma unroll
            for (int nt = 0; nt < 2; ++nt) {
                int n = (2 * w + nt) * 32 + lr;
                f16x8 Bhi = *(const f16x8*)&W2T_hi[n * 256 + kk];
                f16x8 Blo = *(const f16x8*)&W2T_lo[n * 256 + kk];
                #pragma unroll
                for (int m = 0; m < 4; ++m) {
                    f16x8 Af = half ? A1[m] : A0[m];
                    acc[m][nt] = __builtin_amdgcn_mfma_f32_32x32x16_f16(Af, Bhi, acc[m][nt], 0, 0, 0);
                    acc[m][nt] = __builtin_amdgcn_mfma_f32_32x32x16_f16(Af, Blo, acc[m][nt], 0, 0, 0);
                }
            }
        }
    }

    // ---- layer 3: elu(z2)*W3, per-lane partials -> LDS (overlay) -> reduce ----
    float w3v0 = W3[c0], w3v1 = W3[c1];
    float b3v = b3[0];
    float* pb = (float*)smem;

    __syncthreads();   // all h1x reads done before overlay writes

    #pragma unroll
    for (int m = 0; m < 4; ++m) {
        float pv[16];
        #pragma unroll
        for (int r = 0; r < 16; ++r) {
            float z0 = elu_f(acc[m][0][r]);
            float z1v = elu_f(acc[m][1][r]);
            pv[r] = z0 * w3v0 + z1v * w3v1;
        }
        #pragma unroll
        for (int rq = 0; rq < 4; ++rq) {
            int rowbase = m * 32 + 8 * rq + 4 * hh;
            int unit = rowbase >> 2;             // 8m + 2rq + hh
            int phys = unit ^ (lr & 7);
            float4 v = make_float4(pv[rq * 4 + 0], pv[rq * 4 + 1], pv[rq * 4 + 2], pv[rq * 4 + 3]);
            *(float4*)&pb[(w * 32 + lr) * 128 + (phys << 2)] = v;
        }
    }

    __syncthreads();

    // reduce over 4 waves x 32 lanes for each of 128 rows
    {
        int row = tid >> 1;
        int hf = tid & 1;
        float v = 0.f;
        #pragma unroll
        for (int w2 = 0; w2 < 4; ++w2) {
            #pragma unroll
            for (int li = 0; li < 16; ++li) {
                int lx = hf * 16 + li;
                v += pb[(w2 * 32 + lx) * 128 + (((row >> 2) ^ (lx & 7)) << 2) + (row & 3)];
            }
        }
        v += __shfl_xor(v, 1);
        if (hf == 0) {
            int rg = R0 + row;
            if (rg < ND) u[rg] = v + b3v;
        }
    }
}

// ---------------------------------------------------------------------------
// K5: per-session loss + argmax/top-2 precision counts
// ---------------------------------------------------------------------------
template <int PER>
__global__ void session_kernel(const float* __restrict__ u, const int* __restrict__ clickSub,
                               const int* __restrict__ clickIdx, const int* __restrict__ dispIdx,
                               float* __restrict__ pLoss, int* __restrict__ pP1,
                               int* __restrict__ pP2, int S) {
    int s = blockIdx.x * blockDim.x + threadIdx.x;
    float lossv = 0.f; int p1 = 0, p2 = 0;
    if (s < S) {
        int base = s * PER;
        float ev[PER]; int it[PER];
        float sum_exp = 0.f;
        #pragma unroll
        for (int i = 0; i < PER; ++i) {
            float uu = u[base + i];
            ev[i] = expf(uu);
            sum_exp += ev[i];
            it[i] = dispIdx[(size_t)(base + i) * 2 + 1];
        }
        int crow = clickSub[s];
        lossv = -u[crow] + logf(sum_exp + 1.f);

        float bestv = -1.f; int besti = 0x7FFFFFFF;
        float secv = -1.f;  int seci = 0x7FFFFFFF;
        int ndist = 0;
        #pragma unroll
        for (int i = 0; i < PER; ++i) {
            bool first = true; float tot = 0.f;
            #pragma unroll
            for (int j = 0; j < PER; ++j) {
                if (it[j] == it[i]) { tot += ev[j]; if (j < i) first = false; }
            }
            if (first) {
                ndist++;
                if (tot > bestv || (tot == bestv && it[i] < besti)) {
                    secv = bestv; seci = besti;
                    bestv = tot;  besti = it[i];
                } else if (tot > secv || (tot == secv && it[i] < seci)) {
                    secv = tot; seci = it[i];
                }
            }
        }
        if (ndist < 2) seci = (besti == 0) ? 1 : 0;
        int citem = clickIdx[s * 2 + 1];
        p1 = (citem == besti) ? 1 : 0;
        p2 = (citem == besti || citem == seci) ? 1 : 0;
    }
    __shared__ float rf[TPB]; __shared__ int r1[TPB]; __shared__ int r2[TPB];
    int t = threadIdx.x;
    rf[t] = lossv; r1[t] = p1; r2[t] = p2;
    __syncthreads();
    for (int off = TPB / 2; off > 0; off >>= 1) {
        if (t < off) { rf[t] += rf[t + off]; r1[t] += r1[t + off]; r2[t] += r2[t + off]; }
        __syncthreads();
    }
    if (t == 0) { pLoss[blockIdx.x] = rf[0]; pP1[blockIdx.x] = r1[0]; pP2[blockIdx.x] = r2[0]; }
}

// ---------------------------------------------------------------------------
// K6: reduce block partials, emit the 7 scalar outputs.
// ---------------------------------------------------------------------------
__global__ void finalize_kernel(const float* __restrict__ pLoss, const int* __restrict__ pP1,
                                const int* __restrict__ pP2, int nb, float event_cnt,
                                float* __restrict__ out) {
    __shared__ float sf[TPB]; __shared__ int s1[TPB]; __shared__ int s2[TPB];
    int t = threadIdx.x;
    float lf = 0.f; int a1 = 0, a2 = 0;
    for (int i = t; i < nb; i += TPB) { lf += pLoss[i]; a1 += pP1[i]; a2 += pP2[i]; }
    sf[t] = lf; s1[t] = a1; s2[t] = a2;
    __syncthreads();
    for (int off = TPB / 2; off > 0; off >>= 1) {
        if (t < off) { sf[t] += sf[t + off]; s1[t] += s1[t + off]; s2[t] += s2[t + off]; }
        __syncthreads();
    }
    if (t == 0) {
        float ls = sf[0];
        float p1 = (float)s1[0];
        float p2 = (float)s2[0];
        out[0] = ls / event_cnt;
        out[1] = p1 / event_cnt;
        out[2] = p2 / event_cnt;
        out[3] = ls;
        out[4] = p1;
        out[5] = p2;
        out[6] = event_cnt;
    }
}

// ---------------------------------------------------------------------------
extern "C" void kernel_launch(void* const* d_in, const int* in_sizes, int n_in,
                              void* d_out, int out_size, void* d_ws, size_t ws_size,
                              hipStream_t stream) {
    const float* dispF    = (const float*)d_in[0];
    const float* Xs       = (const float*)d_in[1];
    const float* W1       = (const float*)d_in[2];
    const float* b1       = (const float*)d_in[3];
    const float* W2       = (const float*)d_in[4];
    const float* b2       = (const float*)d_in[5];
    const float* W3       = (const float*)d_in[6];
    const float* b3       = (const float*)d_in[7];
    const int*   tril     = (const int*)d_in[8];
    const int*   clickSub = (const int*)d_in[11];
    const int*   clickIdx = (const int*)d_in[12];
    const int*   dispIdx  = (const int*)d_in[13];

    const int S    = in_sizes[11];
    const int ND   = in_sizes[10];
    const int F    = in_sizes[1] / S;            // 64
    const int H    = in_sizes[3];                // 256
    const int NT   = in_sizes[9];
    const int BAND = NT / S;                     // 20
    const int PW   = in_sizes[2] / (F * H) - 1;  // 10
    const int per  = ND / S;                     // 10

    float* ws    = (float*)d_ws;
    float* hist  = ws;                                   // S*F
    float* W1sum = hist + (size_t)S * F;                 // F*H
    float* Ahist = W1sum + (size_t)F * H;                // S*H
    float* u     = Ahist + (size_t)S * H;                // ND (+pad)
    const int nb5 = (S + TPB - 1) / TPB;
    float* pLoss = u + ((size_t)ND + 128);               // nb5
    int*   pP1   = (int*)(pLoss + nb5);
    int*   pP2   = pP1 + nb5;
    // 16B-aligned fp16 region
    size_t f32_used = (size_t)(pP2 + nb5 - (int*)ws);
    f32_used = (f32_used + 3) & ~(size_t)3;
    _Float16* W1bT_hi = (_Float16*)(ws + f32_used);      // 256*64
    _Float16* W1bT_lo = W1bT_hi + 64 * 256;
    _Float16* W2T_hi  = W1bT_lo + 64 * 256;              // 256*256
    _Float16* W2T_lo  = W2T_hi + 256 * 256;

    const int PWF = PW * F;                              // 640

    hist_kernel<<<(S * F + TPB - 1) / TPB, TPB, 0, stream>>>(Xs, tril, hist, S, BAND, F);
    w1sum_kernel<<<(F * H + TPB - 1) / TPB, TPB, 0, stream>>>(W1, W1sum, F, H, PW);
    prep_kernel<<<(64 * 256 + 256 * 256 + TPB - 1) / TPB, TPB, 0, stream>>>(
        W1, W2, W1bT_hi, W1bT_lo, W2T_hi, W2T_lo, PWF);
    ahist_kernel<<<(S + 31) / 32, TPB, 0, stream>>>(hist, W1sum, b1, Ahist, S);
    mlp_mfma_kernel<<<(ND + 127) / 128, TPB, 0, stream>>>(
        dispF, Ahist, W1bT_hi, W1bT_lo, W2T_hi, W2T_lo, b2, W3, b3, u,
        ND, per, 1.0f / (float)per);
    session_kernel<10><<<nb5, TPB, 0, stream>>>(u, clickSub, clickIdx, dispIdx, pLoss, pP1, pP2, S);
    finalize_kernel<<<1, TPB, 0, stream>>>(pLoss, pP1, pP2, nb5, (float)S, (float*)d_out);
}